// Round 9
// baseline (1940.892 us; speedup 1.0000x reference)
//
#include <hip/hip_runtime.h>
#include <math.h>

#define DEVFN __device__ __forceinline__

typedef short  s16x8 __attribute__((ext_vector_type(8)));
typedef float  f32x4 __attribute__((ext_vector_type(4)));

constexpr int C     = 768;
constexpr int NROWS = 25216;   // 197*128
constexpr int NCL   = 128;     // class rows (features[0:1])
constexpr int KCB   = 4096;    // codes per codebook
constexpr int KOUT  = 8192;    // distance columns (class | feat)
constexpr int TK    = 3;
constexpr int NT    = 24;      // K-steps (768/32)
constexpr int MT    = 197;     // row tiles (128 rows each)
constexpr int NTB   = 16;      // col tiles per codebook (256 cols each)

// output layout (flat, return order)
constexpr long long QUANT_OFF  = 1;
constexpr long long QUANT_SZ   = (long long)NROWS * TK * C;         // 58,097,664
constexpr long long CLPERP_OFF = QUANT_OFF + QUANT_SZ;
constexpr long long FTPERP_OFF = CLPERP_OFF + 1;
constexpr long long CLAVG_OFF  = FTPERP_OFF + 1;
constexpr long long FTAVG_OFF  = CLAVG_OFF + KCB;
constexpr long long ENC_OFF    = FTAVG_OFF + KCB;
constexpr long long DIST_OFF   = ENC_OFF + (long long)NROWS * TK;   // 58,181,507

// packed pre-split bf16 scratch + top-3 partials (all in the quant output
// region, written only later by gather_kernel; ~142 MB needed, 232 MB avail)
constexpr size_t XS_ELE = (size_t)MT * NT * 4096;        // 128x32 tiles
constexpr size_t ES_ELE = (size_t)2 * NTB * NT * 8192;   // 256x32 tiles
constexpr size_t PV_ELE = (size_t)NROWS * 64 * 3;        // 4,841,472 (val or idx)

constexpr float FMAXV = 3.4028234663852886e38f;
// Padding value: largest float that stays FINITE through a bf16 round-trip
// (0x7F7F0000). FLT_MAX rounds to +inf in bf16 -> inf-inf = nan in the
// harness compare.
constexpr float PADV  = 3.3895313892515355e38f;

DEVFN void gload_lds16(const void* g, void* l) {
    __builtin_amdgcn_global_load_lds(
        (const __attribute__((address_space(1))) unsigned*)g,
        (__attribute__((address_space(3))) unsigned*)l, 16, 0, 0);
}

// ---------------- top-3 primitives (BRANCHLESS: cndmask, no divergence) ----
DEVFN bool better(float v, int i, float bv, int bi) {
    return (v < bv) | ((v == bv) & (i < bi));  // stable: smaller index wins ties
}
DEVFN void ins3(float v, int i, float& v0, int& i0, float& v1, int& i1, float& v2, int& i2) {
    const bool b0 = better(v, i, v0, i0);
    const bool b1 = better(v, i, v1, i1);
    const bool b2 = better(v, i, v2, i2);
    // sorted invariant (v0<=v1<=v2 in 'better' order) gives b0 => b1 => b2
    const float nv1 = b0 ? v0 : (b1 ? v : v1);
    const int   ni1 = b0 ? i0 : (b1 ? i : i1);
    const float nv2 = b1 ? v1 : (b2 ? v : v2);
    const int   ni2 = b1 ? i1 : (b2 ? i : i2);
    v0 = b0 ? v : v0;  i0 = b0 ? i : i0;
    v1 = nv1;          i1 = ni1;
    v2 = nv2;          i2 = ni2;
}

// ---------------- init ----------------
__global__ void init_kernel(float* counts) {
    int i = blockIdx.x * blockDim.x + threadIdx.x;
    if (i < KOUT) counts[i] = 0.0f;
}

// ---------------- row norms (features + both codebooks) ----------------
__global__ void norms_kernel(const float* __restrict__ X,
                             const float* __restrict__ CE,
                             const float* __restrict__ FE,
                             float* __restrict__ xnorm,
                             float* __restrict__ enorm) {
    int row  = blockIdx.x * 4 + (threadIdx.x >> 6);
    int lane = threadIdx.x & 63;
    const int TOT = NROWS + 2 * KCB;
    if (row >= TOT) return;
    const float* src; float* dst;
    if (row < NROWS) { src = X + (long long)row * C; dst = xnorm + row; }
    else {
        int r = row - NROWS;
        src = (r < KCB) ? (CE + (long long)r * C) : (FE + (long long)(r - KCB) * C);
        dst = enorm + r;   // [0..4095] class, [4096..8191] feat
    }
    const float4* p = (const float4*)src;
    float s = 0.f;
    for (int j = lane; j < C / 4; j += 64) {
        float4 v = p[j];
        s += v.x*v.x + v.y*v.y + v.z*v.z + v.w*v.w;
    }
    for (int o = 32; o > 0; o >>= 1) s += __shfl_down(s, o);
    if (lane == 0) *dst = s;
}

// ---------------- pre-split: fp32 -> packed swizzled bf16 hi/lo tiles ------
// A tiles: 128x32 (8 KB/plane/tile), B tiles: 256x32 (16 KB/plane/tile).
// Element (r,k) -> byte (r*64 + 2k) ^ ((r&7)<<4) within its tile image.
__global__ __launch_bounds__(256)
void presplit_kernel(const float* __restrict__ X,
                     const float* __restrict__ CE,
                     const float* __restrict__ FE,
                     short* __restrict__ XsH, short* __restrict__ XsL,
                     short* __restrict__ EsH, short* __restrict__ EsL) {
    const int b = blockIdx.x;                    // A: 197*24, then B: 2*16*24
    const float* src; char* dH; char* dL; int nrr;
    if (b < MT * NT) {
        const int tile = b / NT, ks = b % NT;
        src = X + (size_t)tile * 128 * C + ks * 32;
        dH = (char*)(XsH + (size_t)b * 4096);
        dL = (char*)(XsL + (size_t)b * 4096);
        nrr = 2;                                  // 128 rows
    } else {
        const int bb = b - MT * NT;               // 0..767
        const int book = bb / (NTB * NT);
        const int rem  = bb % (NTB * NT);
        const int tile = rem / NT, ks = rem % NT;
        src = (book ? FE : CE) + (size_t)tile * 256 * C + ks * 32;
        dH = (char*)(EsH + (size_t)bb * 8192);
        dL = (char*)(EsL + (size_t)bb * 8192);
        nrr = 4;                                  // 256 rows
    }
    const int tid = threadIdx.x;
    const int row = tid >> 2, oc = tid & 3;       // base row, k-octet
    for (int rr = 0; rr < nrr; ++rr) {
        const int r = row + rr * 64;
        const float* s = src + (size_t)r * C + oc * 8;
        float4 v0 = *(const float4*)s;
        float4 v1 = *(const float4*)(s + 4);
        float f[8] = {v0.x, v0.y, v0.z, v0.w, v1.x, v1.y, v1.z, v1.w};
        s16x8 hi, lo;
        #pragma unroll
        for (int q = 0; q < 8; ++q) {
            unsigned u = __float_as_uint(f[q]);
            hi[q] = (short)(u >> 16);
            lo[q] = (short)(__float_as_uint(f[q] - __uint_as_float(u & 0xffff0000u)) >> 16);
        }
        const int off = (r * 64 + oc * 16) ^ ((r & 7) << 4);
        *(s16x8*)(dH + off) = hi;
        *(s16x8*)(dL + off) = lo;
    }
}

// ---------------- distance GEMM via bf16x3 MFMA + fused LOCAL top-3 --------
// BM=128 x BN=256, 8 waves (2x4 of 64x64), BK=32, double-buffered 96 KB LDS.
// Main loop identical to r7. Epilogue: per (row, 64-col half) BRANCHLESS
// top-3 (4 local ins3 + 4-step 16-lane shuffle merge, 16 independent chains
// for ILP) -> (val,idx) partials. dist written (output) but never re-read.
__global__ __launch_bounds__(512, 2)
void gemm_dist_kernel(const short* __restrict__ XsH, const short* __restrict__ XsL,
                      const short* __restrict__ EsH, const short* __restrict__ EsL,
                      const float* __restrict__ xnorm,
                      const float* __restrict__ enorm,
                      float* __restrict__ dist,
                      float* __restrict__ pval,
                      int* __restrict__ pidx) {
    // per buffer: AH 8K | AL 8K | BH 16K | BL 16K = 48 KB; x2 buffers
    __shared__ __align__(16) char smem[2 * 49152];

    // XCD-aware bijective swizzle: 3152 blocks, 3152 % 8 == 0, chunk = 394
    const int orig = blockIdx.y * gridDim.x + blockIdx.x;   // gridDim.x = 16
    const int wg   = (orig & 7) * 394 + (orig >> 3);
    const int mt = wg >> 4, nt = wg & 15;

    const int m0 = mt * 128, n0 = nt * 256;
    const int colbase = (mt == 0) ? 0 : KCB;
    const int btile = ((mt == 0) ? 0 : NTB) + nt;
    const int tid = threadIdx.x, l = tid & 63, w = tid >> 6;   // 8 waves
    const int wy = w >> 2, wx = w & 3;

    // ---- staging: 48 wave-chunks of 1 KB; wave w owns chunks w*6..w*6+5
    const char* sbase[6]; size_t sstr[6]; int ldso[6];
    #pragma unroll
    for (int i = 0; i < 6; ++i) {
        const int wc = w * 6 + i;
        const char* pb; int within; size_t st;
        if (wc < 8)       { pb = (const char*)XsH + (size_t)mt * NT * 8192;     within = wc * 1024;        st = 8192;  }
        else if (wc < 16) { pb = (const char*)XsL + (size_t)mt * NT * 8192;     within = (wc - 8) * 1024;  st = 8192;  }
        else if (wc < 32) { pb = (const char*)EsH + (size_t)btile * NT * 16384; within = (wc - 16) * 1024; st = 16384; }
        else              { pb = (const char*)EsL + (size_t)btile * NT * 16384; within = (wc - 32) * 1024; st = 16384; }
        sbase[i] = pb + within + l * 16;
        sstr[i]  = st;
        ldso[i]  = wc * 1024 + l * 16;
    }
    auto STAGE = [&](int buf, int t) {
        #pragma unroll
        for (int i = 0; i < 6; ++i)
            gload_lds16(sbase[i] + (size_t)t * sstr[i], smem + buf * 49152 + ldso[i]);
    };

    // fragment geometry: wave (wy,wx) owns a 64x64 sub-tile of 128x256
    const int arow = wy * 64 + (l & 15);
    const int brow = wx * 64 + (l & 15);
    const int abase = (arow * 64 + ((l >> 4) * 16)) ^ ((l & 7) << 4);
    const int bbase = (brow * 64 + ((l >> 4) * 16)) ^ ((l & 7) << 4);

    f32x4 acc[4][4];
    #pragma unroll
    for (int i = 0; i < 4; ++i)
        #pragma unroll
        for (int j = 0; j < 4; ++j) acc[i][j] = (f32x4){0.f, 0.f, 0.f, 0.f};

    STAGE(0, 0);
    int cur = 0;
    for (int t = 0; t < NT; ++t) {
        if (t + 1 < NT) {
            STAGE(cur ^ 1, t + 1);                       // fly across this whole step
            asm volatile("s_waitcnt vmcnt(6)" ::: "memory");   // tile t's 6 done
        } else {
            asm volatile("s_waitcnt vmcnt(0)" ::: "memory");
        }
        __builtin_amdgcn_s_barrier();                    // raw: no implicit drain
        __builtin_amdgcn_sched_barrier(0);

        const char* sb = smem + cur * 49152;
        s16x8 ah[4], bh[4];
        #pragma unroll
        for (int i = 0; i < 4; ++i) ah[i] = *(const s16x8*)(sb + abase + i * 1024);
        #pragma unroll
        for (int j = 0; j < 4; ++j) bh[j] = *(const s16x8*)(sb + 16384 + bbase + j * 1024);
        #pragma unroll
        for (int i = 0; i < 4; ++i)
            #pragma unroll
            for (int j = 0; j < 4; ++j)
                acc[i][j] = __builtin_amdgcn_mfma_f32_16x16x32_bf16(ah[i], bh[j], acc[i][j], 0, 0, 0);

        s16x8 al[4];
        #pragma unroll
        for (int i = 0; i < 4; ++i) al[i] = *(const s16x8*)(sb + 8192 + abase + i * 1024);
        #pragma unroll
        for (int i = 0; i < 4; ++i)
            #pragma unroll
            for (int j = 0; j < 4; ++j)
                acc[i][j] = __builtin_amdgcn_mfma_f32_16x16x32_bf16(al[i], bh[j], acc[i][j], 0, 0, 0);

        s16x8 bl[4];
        #pragma unroll
        for (int j = 0; j < 4; ++j) bl[j] = *(const s16x8*)(sb + 32768 + bbase + j * 1024);
        #pragma unroll
        for (int i = 0; i < 4; ++i)
            #pragma unroll
            for (int j = 0; j < 4; ++j)
                acc[i][j] = __builtin_amdgcn_mfma_f32_16x16x32_bf16(ah[i], bl[j], acc[i][j], 0, 0, 0);

        __builtin_amdgcn_sched_barrier(0);
        asm volatile("s_waitcnt lgkmcnt(0)" ::: "memory");  // my reads of buf done
        __builtin_amdgcn_s_barrier();                        // all waves done reading
        cur ^= 1;
    }

    // ---- epilogue: d = (xn + en) - 2*dot ; C/D map: col=lane&15, row=(lane>>4)*4+q
    // For fixed (i,q) the row's 64 cols of this wave live in its 16-lane
    // group (4 j x 16 lc). 16 independent branchless top-3 chains.
    const int lr = (l >> 4) * 4;
    const int lc = l & 15;
    const int halfid = nt * 4 + wx;              // 0..63 column-half id
    float en_r[4];
    #pragma unroll
    for (int j = 0; j < 4; ++j) en_r[j] = enorm[colbase + n0 + wx * 64 + j * 16 + lc];
    #pragma unroll
    for (int i = 0; i < 4; ++i) {
        #pragma unroll
        for (int q = 0; q < 4; ++q) {
            const int gm = m0 + wy * 64 + i * 16 + lr + q;
            const float xnv = xnorm[gm];
            float* o = dist + (long long)gm * KOUT + colbase + n0 + wx * 64 + lc;
            float tv0 = FMAXV, tv1 = FMAXV, tv2 = FMAXV;
            int   ti0 = 0x7fffffff, ti1 = 0x7fffffff, ti2 = 0x7fffffff;
            #pragma unroll
            for (int j = 0; j < 4; ++j) {
                const float dvv = (xnv + en_r[j]) - 2.0f * acc[i][j][q];
                o[j * 16] = dvv;                  // scalar: dist base is 4B-aligned only
                ins3(dvv, n0 + wx * 64 + j * 16 + lc, tv0, ti0, tv1, ti1, tv2, ti2);
            }
            #pragma unroll
            for (int off = 8; off > 0; off >>= 1) {   // merge within 16-lane group
                float u0 = __shfl_down(tv0, off), u1 = __shfl_down(tv1, off), u2 = __shfl_down(tv2, off);
                int   j0 = __shfl_down(ti0, off), j1 = __shfl_down(ti1, off), j2 = __shfl_down(ti2, off);
                ins3(u0, j0, tv0, ti0, tv1, ti1, tv2, ti2);
                ins3(u1, j1, tv0, ti0, tv1, ti1, tv2, ti2);
                ins3(u2, j2, tv0, ti0, tv1, ti1, tv2, ti2);
            }
            if (lc == 0) {
                const long long pb = ((long long)gm * 64 + halfid) * 3;
                pval[pb + 0] = tv0; pval[pb + 1] = tv1; pval[pb + 2] = tv2;
                pidx[pb + 0] = ti0; pidx[pb + 1] = ti1; pidx[pb + 2] = ti2;
            }
        }
    }

    // ---- fused pad: this block's mirror 128x256 stripe in the other codebook's half
    const int padbase = (mt == 0) ? KCB : 0;
    for (int r2 = w; r2 < 128; r2 += 8) {
        float* p = dist + (long long)(m0 + r2) * KOUT + padbase + n0;
        p[l] = PADV; p[l + 64] = PADV; p[l + 128] = PADV; p[l + 192] = PADV;
    }
}

// ---------------- top-3 merge: 64 sorted per-half partials -> final --------
__global__ __launch_bounds__(256)
void topk_merge_kernel(const float* __restrict__ pval,
                       const int* __restrict__ pidx,
                       int* __restrict__ idxbuf,
                       float* __restrict__ out,
                       float* __restrict__ counts) {
    int row = blockIdx.x * 4 + (threadIdx.x >> 6);
    if (row >= NROWS) return;
    const int lane = threadIdx.x & 63;
    const int colbase = (row < NCL) ? 0 : KCB;
    const long long pb = ((long long)row * 64 + lane) * 3;
    float v0 = pval[pb + 0], v1 = pval[pb + 1], v2 = pval[pb + 2];
    int   i0 = pidx[pb + 0], i1 = pidx[pb + 1], i2 = pidx[pb + 2];
    #pragma unroll
    for (int off = 32; off > 0; off >>= 1) {
        float w0 = __shfl_down(v0, off), w1 = __shfl_down(v1, off), w2 = __shfl_down(v2, off);
        int   j0 = __shfl_down(i0, off), j1 = __shfl_down(i1, off), j2 = __shfl_down(i2, off);
        ins3(w0, j0, v0, i0, v1, i1, v2, i2);
        ins3(w1, j1, v0, i0, v1, i1, v2, i2);
        ins3(w2, j2, v0, i0, v1, i1, v2, i2);
    }
    if (lane == 0) {
        long long rt = (long long)row * TK;
        idxbuf[rt + 0] = i0; idxbuf[rt + 1] = i1; idxbuf[rt + 2] = i2;
        out[ENC_OFF + rt + 0] = (float)(i0 + colbase);
        out[ENC_OFF + rt + 1] = (float)(i1 + colbase);
        out[ENC_OFF + rt + 2] = (float)(i2 + colbase);
        atomicAdd(&counts[i0 + colbase], 1.0f);
        atomicAdd(&counts[i1 + colbase], 1.0f);
        atomicAdd(&counts[i2 + colbase], 1.0f);
    }
}

// ---------------- gather + q_st + per-row SSE partial (no atomics) ----------------
__global__ __launch_bounds__(192)
void gather_kernel(const float* __restrict__ X,
                   const float* __restrict__ CE,
                   const float* __restrict__ FE,
                   const int* __restrict__ idxbuf,
                   float* __restrict__ out,
                   float* __restrict__ partials) {
    const int row = blockIdx.x;            // 0..25215
    const int tid = threadIdx.x;           // 0..191: one float4 column of the row
    const float4 xv = ((const float4*)(X + (size_t)row * C))[tid];
    const float* Ebase = (row < NCL) ? CE : FE;
    const long long rt0 = (long long)row * TK;
    float s = 0.f;
    #pragma unroll
    for (int t = 0; t < TK; ++t) {
        const int id = idxbuf[rt0 + t];
        const float4 ev = ((const float4*)(Ebase + (size_t)id * C))[tid];
        const float d0 = ev.x - xv.x, d1 = ev.y - xv.y, d2 = ev.z - xv.z, d3 = ev.w - xv.w;
        s += d0*d0 + d1*d1 + d2*d2 + d3*d3;
        // q_st = x + (quant - x), exactly the reference's float ops.
        float* q = out + QUANT_OFF + (rt0 + t) * C + tid * 4;
        q[0] = xv.x + d0; q[1] = xv.y + d1; q[2] = xv.z + d2; q[3] = xv.w + d3;
    }
    #pragma unroll
    for (int o = 32; o > 0; o >>= 1) s += __shfl_down(s, o);
    __shared__ float red[3];
    const int lane = tid & 63, w = tid >> 6;
    if (lane == 0) red[w] = s;
    __syncthreads();
    if (tid == 0) partials[row] = red[0] + red[1] + red[2];
}

// ---------------- finalize: avg_probs, perplexity, loss ----------------
__global__ void finalize_kernel(const float* __restrict__ counts,
                                const float* __restrict__ partials,
                                float* __restrict__ out) {
    __shared__ float  red[2][4];
    __shared__ double redd[2][4];
    int tid = threadIdx.x, lane = tid & 63, w = tid >> 6;
    float ecl = 0.f, eft = 0.f;
    for (int i = tid; i < KCB; i += blockDim.x) {
        float p = counts[i] * (1.0f / 128.0f);
        out[CLAVG_OFF + i] = p;
        ecl += p * logf(p + 1e-10f);
        float qv = counts[KCB + i] * (1.0f / 25088.0f);
        out[FTAVG_OFF + i] = qv;
        eft += qv * logf(qv + 1e-10f);
    }
    double scl = 0.0, sft = 0.0;
    for (int i = tid; i < NROWS; i += blockDim.x) {
        double v = (double)partials[i];
        if (i < NCL) scl += v; else sft += v;
    }
    for (int o = 32; o > 0; o >>= 1) {
        ecl += __shfl_down(ecl, o); eft += __shfl_down(eft, o);
        scl += __shfl_down(scl, o); sft += __shfl_down(sft, o);
    }
    if (lane == 0) { red[0][w] = ecl; red[1][w] = eft; redd[0][w] = scl; redd[1][w] = sft; }
    __syncthreads();
    if (tid == 0) {
        float tcl = red[0][0] + red[0][1] + red[0][2] + red[0][3];
        float tft = red[1][0] + red[1][1] + red[1][2] + red[1][3];
        double dcl = redd[0][0] + redd[0][1] + redd[0][2] + redd[0][3];
        double dft = redd[1][0] + redd[1][1] + redd[1][2] + redd[1][3];
        out[CLPERP_OFF] = expf(-tcl);
        out[FTPERP_OFF] = expf(-tft);
        float cl_loss = 0.25f * (float)(dcl / 294912.0);     // 1*128*3*768
        float ft_loss = 0.25f * (float)(dft / 57802752.0);   // 196*128*3*768
        out[0] = ft_loss + cl_loss;
    }
}

extern "C" void kernel_launch(void* const* d_in, const int* in_sizes, int n_in,
                              void* d_out, int out_size, void* d_ws, size_t ws_size,
                              hipStream_t stream) {
    const float* X  = (const float*)d_in[0];
    const float* CE = (const float*)d_in[1];
    const float* FE = (const float*)d_in[2];
    float* out = (float*)d_out;

    float* ws_f   = (float*)d_ws;
    float* xnorm  = ws_f;                         // 25216 (reused as SSE partials)
    float* enorm  = ws_f + NROWS;                 // 8192
    float* counts = ws_f + NROWS + KOUT;          // 8192
    int*   idxbuf = (int*)(ws_f + NROWS + 2 * KOUT);  // 75648 ints
    float* ssepart = xnorm;                       // xnorm dead after gemm; reuse
    float* dist   = out + DIST_OFF;

    // scratch inside the quant output region (dead until gather):
    // bf16 planes (~103 MB) + top-3 partials (38.7 MB) < 232 MB
    short* XsH = (short*)(out + 4);
    short* XsL = XsH + XS_ELE;
    short* EsH = XsL + XS_ELE;
    short* EsL = EsH + ES_ELE;
    float* pval = (float*)(EsL + ES_ELE);         // 16B-aligned (all plane sizes %16==0)
    int*   pidx = (int*)(pval + PV_ELE);

    init_kernel<<<32, 256, 0, stream>>>(counts);
    norms_kernel<<<(NROWS + 2 * KCB) / 4, 256, 0, stream>>>(X, CE, FE, xnorm, enorm);
    presplit_kernel<<<MT * NT + 2 * NTB * NT, 256, 0, stream>>>(X, CE, FE, XsH, XsL, EsH, EsL);
    gemm_dist_kernel<<<dim3(NTB, MT), 512, 0, stream>>>(XsH, XsL, EsH, EsL, xnorm, enorm,
                                                        dist, pval, pidx);
    topk_merge_kernel<<<NROWS / 4, 256, 0, stream>>>(pval, pidx, idxbuf, out, counts);
    gather_kernel<<<NROWS, 192, 0, stream>>>(X, CE, FE, idxbuf, out, ssepart);
    finalize_kernel<<<1, 256, 0, stream>>>(counts, ssepart, out);
}

// Round 10
// 1773.438 us; speedup vs baseline: 1.0944x; 1.0944x over previous
//
#include <hip/hip_runtime.h>
#include <math.h>

#define DEVFN __device__ __forceinline__

typedef short  s16x8 __attribute__((ext_vector_type(8)));
typedef float  f32x4 __attribute__((ext_vector_type(4)));

constexpr int C     = 768;
constexpr int NROWS = 25216;   // 197*128
constexpr int NCL   = 128;     // class rows (features[0:1])
constexpr int KCB   = 4096;    // codes per codebook
constexpr int KOUT  = 8192;    // distance columns (class | feat)
constexpr int TK    = 3;
constexpr int NT    = 24;      // K-steps (768/32)
constexpr int MT    = 197;     // row tiles (128 rows each)
constexpr int NTB   = 16;      // col tiles per codebook (256 cols each)

// output layout (flat, return order)
constexpr long long QUANT_OFF  = 1;
constexpr long long QUANT_SZ   = (long long)NROWS * TK * C;         // 58,097,664
constexpr long long CLPERP_OFF = QUANT_OFF + QUANT_SZ;
constexpr long long FTPERP_OFF = CLPERP_OFF + 1;
constexpr long long CLAVG_OFF  = FTPERP_OFF + 1;
constexpr long long FTAVG_OFF  = CLAVG_OFF + KCB;
constexpr long long ENC_OFF    = FTAVG_OFF + KCB;
constexpr long long DIST_OFF   = ENC_OFF + (long long)NROWS * TK;   // 58,181,507
// DIST byte offset mod 16 == 12  ->  column k==1 of every row is 16B-aligned.

// packed pre-split bf16 scratch (lives in the quant output region, which is
// written only later by gather_kernel; 103 MB needed, 232 MB available)
constexpr size_t XS_ELE = (size_t)MT * NT * 4096;        // 128x32 tiles
constexpr size_t ES_ELE = (size_t)2 * NTB * NT * 8192;   // 256x32 tiles

constexpr float FMAXV = 3.4028234663852886e38f;
// Padding value: largest float that stays FINITE through a bf16 round-trip
// (0x7F7F0000). FLT_MAX rounds to +inf in bf16 -> inf-inf = nan in the
// harness compare.
constexpr float PADV  = 3.3895313892515355e38f;

DEVFN void gload_lds16(const void* g, void* l) {
    __builtin_amdgcn_global_load_lds(
        (const __attribute__((address_space(1))) unsigned*)g,
        (__attribute__((address_space(3))) unsigned*)l, 16, 0, 0);
}

// ---------------- top-3 primitives (BRANCHLESS: cndmask, no divergence) ----
DEVFN bool better(float v, int i, float bv, int bi) {
    return (v < bv) | ((v == bv) & (i < bi));  // stable: smaller index wins ties
}
DEVFN void ins3(float v, int i, float& v0, int& i0, float& v1, int& i1, float& v2, int& i2) {
    const bool b0 = better(v, i, v0, i0);
    const bool b1 = better(v, i, v1, i1);
    const bool b2 = better(v, i, v2, i2);
    // sorted invariant (v0<=v1<=v2 in 'better' order) gives b0 => b1 => b2
    const float nv1 = b0 ? v0 : (b1 ? v : v1);
    const int   ni1 = b0 ? i0 : (b1 ? i : i1);
    const float nv2 = b1 ? v1 : (b2 ? v : v2);
    const int   ni2 = b1 ? i1 : (b2 ? i : i2);
    v0 = b0 ? v : v0;  i0 = b0 ? i : i0;
    v1 = nv1;          i1 = ni1;
    v2 = nv2;          i2 = ni2;
}

// ---------------- init ----------------
__global__ void init_kernel(float* counts) {
    int i = blockIdx.x * blockDim.x + threadIdx.x;
    if (i < KOUT) counts[i] = 0.0f;
}

// ---------------- row norms (features + both codebooks) ----------------
__global__ void norms_kernel(const float* __restrict__ X,
                             const float* __restrict__ CE,
                             const float* __restrict__ FE,
                             float* __restrict__ xnorm,
                             float* __restrict__ enorm) {
    int row  = blockIdx.x * 4 + (threadIdx.x >> 6);
    int lane = threadIdx.x & 63;
    const int TOT = NROWS + 2 * KCB;
    if (row >= TOT) return;
    const float* src; float* dst;
    if (row < NROWS) { src = X + (long long)row * C; dst = xnorm + row; }
    else {
        int r = row - NROWS;
        src = (r < KCB) ? (CE + (long long)r * C) : (FE + (long long)(r - KCB) * C);
        dst = enorm + r;   // [0..4095] class, [4096..8191] feat
    }
    const float4* p = (const float4*)src;
    float s = 0.f;
    for (int j = lane; j < C / 4; j += 64) {
        float4 v = p[j];
        s += v.x*v.x + v.y*v.y + v.z*v.z + v.w*v.w;
    }
    for (int o = 32; o > 0; o >>= 1) s += __shfl_down(s, o);
    if (lane == 0) *dst = s;
}

// ---------------- pre-split: fp32 -> packed swizzled bf16 hi/lo tiles ------
// A tiles: 128x32 (8 KB/plane/tile), B tiles: 256x32 (16 KB/plane/tile).
// Element (r,k) -> byte (r*64 + 2k) ^ ((r&7)<<4) within its tile image.
__global__ __launch_bounds__(256)
void presplit_kernel(const float* __restrict__ X,
                     const float* __restrict__ CE,
                     const float* __restrict__ FE,
                     short* __restrict__ XsH, short* __restrict__ XsL,
                     short* __restrict__ EsH, short* __restrict__ EsL) {
    const int b = blockIdx.x;                    // A: 197*24, then B: 2*16*24
    const float* src; char* dH; char* dL; int nrr;
    if (b < MT * NT) {
        const int tile = b / NT, ks = b % NT;
        src = X + (size_t)tile * 128 * C + ks * 32;
        dH = (char*)(XsH + (size_t)b * 4096);
        dL = (char*)(XsL + (size_t)b * 4096);
        nrr = 2;                                  // 128 rows
    } else {
        const int bb = b - MT * NT;               // 0..767
        const int book = bb / (NTB * NT);
        const int rem  = bb % (NTB * NT);
        const int tile = rem / NT, ks = rem % NT;
        src = (book ? FE : CE) + (size_t)tile * 256 * C + ks * 32;
        dH = (char*)(EsH + (size_t)bb * 8192);
        dL = (char*)(EsL + (size_t)bb * 8192);
        nrr = 4;                                  // 256 rows
    }
    const int tid = threadIdx.x;
    const int row = tid >> 2, oc = tid & 3;       // base row, k-octet
    for (int rr = 0; rr < nrr; ++rr) {
        const int r = row + rr * 64;
        const float* s = src + (size_t)r * C + oc * 8;
        float4 v0 = *(const float4*)s;
        float4 v1 = *(const float4*)(s + 4);
        float f[8] = {v0.x, v0.y, v0.z, v0.w, v1.x, v1.y, v1.z, v1.w};
        s16x8 hi, lo;
        #pragma unroll
        for (int q = 0; q < 8; ++q) {
            unsigned u = __float_as_uint(f[q]);
            hi[q] = (short)(u >> 16);
            lo[q] = (short)(__float_as_uint(f[q] - __uint_as_float(u & 0xffff0000u)) >> 16);
        }
        const int off = (r * 64 + oc * 16) ^ ((r & 7) << 4);
        *(s16x8*)(dH + off) = hi;
        *(s16x8*)(dL + off) = lo;
    }
}

// ---------------- distance GEMM via bf16x3 MFMA ----------------------------
// BM=128 x BN=256, 8 waves (2x4 of 64x64), BK=32, TRIPLE-buffered 144 KB LDS.
// vmcnt(12): tile t's 6 loads (issued 2 full steps ago) are the oldest ->
// guaranteed complete; 12 (t+1, t+2) stay in flight across the MFMA phases.
__global__ __launch_bounds__(512, 2)
void gemm_dist_kernel(const short* __restrict__ XsH, const short* __restrict__ XsL,
                      const short* __restrict__ EsH, const short* __restrict__ EsL,
                      const float* __restrict__ xnorm,
                      const float* __restrict__ enorm,
                      float* __restrict__ dist) {
    // per buffer: AH 8K | AL 8K | BH 16K | BL 16K = 48 KB; x3 buffers
    __shared__ __align__(16) char smem[3 * 49152];

    // XCD-aware bijective swizzle: 3152 blocks, 3152 % 8 == 0, chunk = 394
    const int orig = blockIdx.y * gridDim.x + blockIdx.x;   // gridDim.x = 16
    const int wg   = (orig & 7) * 394 + (orig >> 3);
    const int mt = wg >> 4, nt = wg & 15;

    const int m0 = mt * 128, n0 = nt * 256;
    const int colbase = (mt == 0) ? 0 : KCB;
    const int btile = ((mt == 0) ? 0 : NTB) + nt;
    const int tid = threadIdx.x, l = tid & 63, w = tid >> 6;   // 8 waves
    const int wy = w >> 2, wx = w & 3;

    // ---- staging: 48 wave-chunks of 1 KB; wave w owns chunks w*6..w*6+5
    const char* sbase[6]; size_t sstr[6]; int ldso[6];
    #pragma unroll
    for (int i = 0; i < 6; ++i) {
        const int wc = w * 6 + i;
        const char* pb; int within; size_t st;
        if (wc < 8)       { pb = (const char*)XsH + (size_t)mt * NT * 8192;     within = wc * 1024;        st = 8192;  }
        else if (wc < 16) { pb = (const char*)XsL + (size_t)mt * NT * 8192;     within = (wc - 8) * 1024;  st = 8192;  }
        else if (wc < 32) { pb = (const char*)EsH + (size_t)btile * NT * 16384; within = (wc - 16) * 1024; st = 16384; }
        else              { pb = (const char*)EsL + (size_t)btile * NT * 16384; within = (wc - 32) * 1024; st = 16384; }
        sbase[i] = pb + within + l * 16;
        sstr[i]  = st;
        ldso[i]  = wc * 1024 + l * 16;
    }
    auto STAGE = [&](int buf, int t) {
        #pragma unroll
        for (int i = 0; i < 6; ++i)
            gload_lds16(sbase[i] + (size_t)t * sstr[i], smem + buf * 49152 + ldso[i]);
    };

    // fragment geometry: wave (wy,wx) owns a 64x64 sub-tile of 128x256
    const int arow = wy * 64 + (l & 15);
    const int brow = wx * 64 + (l & 15);
    const int abase = (arow * 64 + ((l >> 4) * 16)) ^ ((l & 7) << 4);
    const int bbase = (brow * 64 + ((l >> 4) * 16)) ^ ((l & 7) << 4);

    f32x4 acc[4][4];
    #pragma unroll
    for (int i = 0; i < 4; ++i)
        #pragma unroll
        for (int j = 0; j < 4; ++j) acc[i][j] = (f32x4){0.f, 0.f, 0.f, 0.f};

    STAGE(0, 0);             // 6 in flight
    STAGE(1, 1);             // 12 in flight
    int cur = 0;
    for (int t = 0; t < NT; ++t) {
        if (t + 2 < NT) STAGE((cur + 2 >= 3) ? cur - 1 : cur + 2, t + 2);  // (t+2)%3

        // wait: tile t's 6 are the oldest outstanding; in-order retirement
        // means "<=N outstanding" completes the oldest first.
        if (t + 2 < NT)      { asm volatile("s_waitcnt vmcnt(12)" ::: "memory"); }
        else if (t + 1 < NT) { asm volatile("s_waitcnt vmcnt(6)"  ::: "memory"); }
        else                 { asm volatile("s_waitcnt vmcnt(0)"  ::: "memory"); }
        __builtin_amdgcn_s_barrier();                    // raw: no implicit drain
        __builtin_amdgcn_sched_barrier(0);

        const char* sb = smem + cur * 49152;
        s16x8 ah[4], bh[4];
        #pragma unroll
        for (int i = 0; i < 4; ++i) ah[i] = *(const s16x8*)(sb + abase + i * 1024);
        #pragma unroll
        for (int j = 0; j < 4; ++j) bh[j] = *(const s16x8*)(sb + 16384 + bbase + j * 1024);
        #pragma unroll
        for (int i = 0; i < 4; ++i)
            #pragma unroll
            for (int j = 0; j < 4; ++j)
                acc[i][j] = __builtin_amdgcn_mfma_f32_16x16x32_bf16(ah[i], bh[j], acc[i][j], 0, 0, 0);

        s16x8 al[4];
        #pragma unroll
        for (int i = 0; i < 4; ++i) al[i] = *(const s16x8*)(sb + 8192 + abase + i * 1024);
        #pragma unroll
        for (int i = 0; i < 4; ++i)
            #pragma unroll
            for (int j = 0; j < 4; ++j)
                acc[i][j] = __builtin_amdgcn_mfma_f32_16x16x32_bf16(al[i], bh[j], acc[i][j], 0, 0, 0);

        s16x8 bl[4];
        #pragma unroll
        for (int j = 0; j < 4; ++j) bl[j] = *(const s16x8*)(sb + 32768 + bbase + j * 1024);
        #pragma unroll
        for (int i = 0; i < 4; ++i)
            #pragma unroll
            for (int j = 0; j < 4; ++j)
                acc[i][j] = __builtin_amdgcn_mfma_f32_16x16x32_bf16(ah[i], bl[j], acc[i][j], 0, 0, 0);

        __builtin_amdgcn_sched_barrier(0);
        asm volatile("s_waitcnt lgkmcnt(0)" ::: "memory");  // my reads of buf done
        __builtin_amdgcn_s_barrier();                        // all waves done reading
        cur = (cur == 2) ? 0 : cur + 1;
    }

    // ---- epilogue: d = (xn + en) - 2*dot ; C/D map: col=lane&15, row=(lane>>4)*4+q
    const int lr = (l >> 4) * 4;
    const int lc = l & 15;
    float en_r[4];
    #pragma unroll
    for (int j = 0; j < 4; ++j) en_r[j] = enorm[colbase + n0 + wx * 64 + j * 16 + lc];
    #pragma unroll
    for (int i = 0; i < 4; ++i) {
        #pragma unroll
        for (int q = 0; q < 4; ++q) {
            const int gm = m0 + wy * 64 + i * 16 + lr + q;
            const float xnv = xnorm[gm];
            float* o = dist + (long long)gm * KOUT + colbase + n0 + wx * 64 + lc;
            #pragma unroll
            for (int j = 0; j < 4; ++j)
                o[j * 16] = (xnv + en_r[j]) - 2.0f * acc[i][j][q];  // scalar: dist base is 4B-aligned only
        }
    }

    // ---- fused pad: this block's mirror 128x256 stripe in the other codebook's half
    const int padbase = (mt == 0) ? KCB : 0;
    for (int r2 = w; r2 < 128; r2 += 8) {
        float* p = dist + (long long)(m0 + r2) * KOUT + padbase + n0;
        p[l] = PADV; p[l + 64] = PADV; p[l + 128] = PADV; p[l + 192] = PADV;
    }
}

// ---------------- top-3: branchless, 16-deep batched loads ----------------
// dist byte offset ≡ 12 (mod 16) -> col 1 of every row is 16B-aligned:
// cols 1..4092 as 1023 aligned float4 in ONE 16-deep batch, tail
// {0,4093,4094,4095} scalar. Rows in REVERSE for LLC-tail locality.
__global__ __launch_bounds__(256, 4)
void topk_kernel(const float* __restrict__ dist,
                 int* __restrict__ idxbuf,
                 float* __restrict__ out,
                 float* __restrict__ counts) {
    int rb = blockIdx.x * 4 + (threadIdx.x >> 6);
    if (rb >= NROWS) return;
    const int row = NROWS - 1 - rb;
    const int lane = threadIdx.x & 63;
    const int colbase = (row < NCL) ? 0 : KCB;
    const float* d = dist + (long long)row * KOUT + colbase;
    float v0 = FMAXV, v1 = FMAXV, v2 = FMAXV;
    int   i0 = 0x7fffffff, i1 = 0x7fffffff, i2 = 0x7fffffff;

    const float4* dv = (const float4*)(d + 1);   // 1023 aligned vectors

    float4 b[16];
    #pragma unroll
    for (int it = 0; it < 15; ++it) b[it] = dv[it * 64 + lane];
    const bool hasLast = (960 + lane) < 1023;
    b[15] = hasLast ? dv[960 + lane]
                    : (float4){FMAXV, FMAXV, FMAXV, FMAXV};
    #pragma unroll
    for (int it = 0; it < 15; ++it) {
        const int k = 1 + (it * 64 + lane) * 4;
        ins3(b[it].x, k,     v0, i0, v1, i1, v2, i2);
        ins3(b[it].y, k + 1, v0, i0, v1, i1, v2, i2);
        ins3(b[it].z, k + 2, v0, i0, v1, i1, v2, i2);
        ins3(b[it].w, k + 3, v0, i0, v1, i1, v2, i2);
    }
    {
        const int k = 1 + (960 + lane) * 4;
        const int kk = hasLast ? k : 0x7ffffff0; // masked entries stay maximal in tie-order
        ins3(b[15].x, kk,     v0, i0, v1, i1, v2, i2);
        ins3(b[15].y, kk + 1, v0, i0, v1, i1, v2, i2);
        ins3(b[15].z, kk + 2, v0, i0, v1, i1, v2, i2);
        ins3(b[15].w, kk + 3, v0, i0, v1, i1, v2, i2);
    }
    if (lane < 4) {                              // cols 0, 4093, 4094, 4095
        const int k = (lane == 0) ? 0 : 4092 + lane;
        ins3(d[k], k, v0, i0, v1, i1, v2, i2);
    }

    #pragma unroll
    for (int off = 32; off > 0; off >>= 1) {
        float w0 = __shfl_down(v0, off), w1 = __shfl_down(v1, off), w2 = __shfl_down(v2, off);
        int   j0 = __shfl_down(i0, off), j1 = __shfl_down(i1, off), j2 = __shfl_down(i2, off);
        ins3(w0, j0, v0, i0, v1, i1, v2, i2);
        ins3(w1, j1, v0, i0, v1, i1, v2, i2);
        ins3(w2, j2, v0, i0, v1, i1, v2, i2);
    }
    if (lane == 0) {
        long long rt = (long long)row * TK;
        idxbuf[rt + 0] = i0; idxbuf[rt + 1] = i1; idxbuf[rt + 2] = i2;
        out[ENC_OFF + rt + 0] = (float)(i0 + colbase);
        out[ENC_OFF + rt + 1] = (float)(i1 + colbase);
        out[ENC_OFF + rt + 2] = (float)(i2 + colbase);
        atomicAdd(&counts[i0 + colbase], 1.0f);
        atomicAdd(&counts[i1 + colbase], 1.0f);
        atomicAdd(&counts[i2 + colbase], 1.0f);
    }
}

// ---------------- gather + q_st + per-row SSE partial (no atomics) ----------------
__global__ __launch_bounds__(192)
void gather_kernel(const float* __restrict__ X,
                   const float* __restrict__ CE,
                   const float* __restrict__ FE,
                   const int* __restrict__ idxbuf,
                   float* __restrict__ out,
                   float* __restrict__ partials) {
    const int row = blockIdx.x;            // 0..25215
    const int tid = threadIdx.x;           // 0..191: one float4 column of the row
    const float4 xv = ((const float4*)(X + (size_t)row * C))[tid];
    const float* Ebase = (row < NCL) ? CE : FE;
    const long long rt0 = (long long)row * TK;
    float s = 0.f;
    #pragma unroll
    for (int t = 0; t < TK; ++t) {
        const int id = idxbuf[rt0 + t];
        const float4 ev = ((const float4*)(Ebase + (size_t)id * C))[tid];
        const float d0 = ev.x - xv.x, d1 = ev.y - xv.y, d2 = ev.z - xv.z, d3 = ev.w - xv.w;
        s += d0*d0 + d1*d1 + d2*d2 + d3*d3;
        // q_st = x + (quant - x), exactly the reference's float ops.
        float* q = out + QUANT_OFF + (rt0 + t) * C + tid * 4;
        q[0] = xv.x + d0; q[1] = xv.y + d1; q[2] = xv.z + d2; q[3] = xv.w + d3;
    }
    #pragma unroll
    for (int o = 32; o > 0; o >>= 1) s += __shfl_down(s, o);
    __shared__ float red[3];
    const int lane = tid & 63, w = tid >> 6;
    if (lane == 0) red[w] = s;
    __syncthreads();
    if (tid == 0) partials[row] = red[0] + red[1] + red[2];
}

// ---------------- finalize: avg_probs, perplexity, loss ----------------
__global__ void finalize_kernel(const float* __restrict__ counts,
                                const float* __restrict__ partials,
                                float* __restrict__ out) {
    __shared__ float  red[2][4];
    __shared__ double redd[2][4];
    int tid = threadIdx.x, lane = tid & 63, w = tid >> 6;
    float ecl = 0.f, eft = 0.f;
    for (int i = tid; i < KCB; i += blockDim.x) {
        float p = counts[i] * (1.0f / 128.0f);
        out[CLAVG_OFF + i] = p;
        ecl += p * logf(p + 1e-10f);
        float qv = counts[KCB + i] * (1.0f / 25088.0f);
        out[FTAVG_OFF + i] = qv;
        eft += qv * logf(qv + 1e-10f);
    }
    double scl = 0.0, sft = 0.0;
    for (int i = tid; i < NROWS; i += blockDim.x) {
        double v = (double)partials[i];
        if (i < NCL) scl += v; else sft += v;
    }
    for (int o = 32; o > 0; o >>= 1) {
        ecl += __shfl_down(ecl, o); eft += __shfl_down(eft, o);
        scl += __shfl_down(scl, o); sft += __shfl_down(sft, o);
    }
    if (lane == 0) { red[0][w] = ecl; red[1][w] = eft; redd[0][w] = scl; redd[1][w] = sft; }
    __syncthreads();
    if (tid == 0) {
        float tcl = red[0][0] + red[0][1] + red[0][2] + red[0][3];
        float tft = red[1][0] + red[1][1] + red[1][2] + red[1][3];
        double dcl = redd[0][0] + redd[0][1] + redd[0][2] + redd[0][3];
        double dft = redd[1][0] + redd[1][1] + redd[1][2] + redd[1][3];
        out[CLPERP_OFF] = expf(-tcl);
        out[FTPERP_OFF] = expf(-tft);
        float cl_loss = 0.25f * (float)(dcl / 294912.0);     // 1*128*3*768
        float ft_loss = 0.25f * (float)(dft / 57802752.0);   // 196*128*3*768
        out[0] = ft_loss + cl_loss;
    }
}

extern "C" void kernel_launch(void* const* d_in, const int* in_sizes, int n_in,
                              void* d_out, int out_size, void* d_ws, size_t ws_size,
                              hipStream_t stream) {
    const float* X  = (const float*)d_in[0];
    const float* CE = (const float*)d_in[1];
    const float* FE = (const float*)d_in[2];
    float* out = (float*)d_out;

    float* ws_f   = (float*)d_ws;
    float* xnorm  = ws_f;                         // 25216 (reused as SSE partials)
    float* enorm  = ws_f + NROWS;                 // 8192
    float* counts = ws_f + NROWS + KOUT;          // 8192
    int*   idxbuf = (int*)(ws_f + NROWS + 2 * KOUT);  // 75648 ints
    float* ssepart = xnorm;                       // xnorm dead after gemm; reuse
    float* dist   = out + DIST_OFF;

    // packed bf16 scratch inside the quant output region (dead until gather)
    short* XsH = (short*)(out + 4);
    short* XsL = XsH + XS_ELE;
    short* EsH = XsL + XS_ELE;
    short* EsL = EsH + ES_ELE;

    init_kernel<<<32, 256, 0, stream>>>(counts);
    norms_kernel<<<(NROWS + 2 * KCB) / 4, 256, 0, stream>>>(X, CE, FE, xnorm, enorm);
    presplit_kernel<<<MT * NT + 2 * NTB * NT, 256, 0, stream>>>(X, CE, FE, XsH, XsL, EsH, EsL);
    gemm_dist_kernel<<<dim3(NTB, MT), 512, 0, stream>>>(XsH, XsL, EsH, EsL, xnorm, enorm, dist);
    topk_kernel<<<NROWS / 4, 256, 0, stream>>>(dist, idxbuf, out, counts);
    gather_kernel<<<NROWS, 192, 0, stream>>>(X, CE, FE, idxbuf, out, ssepart);
    finalize_kernel<<<1, 256, 0, stream>>>(counts, ssepart, out);
}

// Round 11
// 1711.312 us; speedup vs baseline: 1.1342x; 1.0363x over previous
//
#include <hip/hip_runtime.h>
#include <math.h>

#define DEVFN __device__ __forceinline__

typedef short  s16x8 __attribute__((ext_vector_type(8)));
typedef float  f32x4 __attribute__((ext_vector_type(4)));

constexpr int C     = 768;
constexpr int NROWS = 25216;   // 197*128
constexpr int NCL   = 128;     // class rows (features[0:1])
constexpr int KCB   = 4096;    // codes per codebook
constexpr int KOUT  = 8192;    // distance columns (class | feat)
constexpr int TK    = 3;
constexpr int NT    = 24;      // K-steps (768/32)
constexpr int MT    = 197;     // row tiles (128 rows each)
constexpr int NTB   = 16;      // col tiles per codebook (256 cols each)

// output layout (flat, return order)
constexpr long long QUANT_OFF  = 1;
constexpr long long QUANT_SZ   = (long long)NROWS * TK * C;         // 58,097,664
constexpr long long CLPERP_OFF = QUANT_OFF + QUANT_SZ;
constexpr long long FTPERP_OFF = CLPERP_OFF + 1;
constexpr long long CLAVG_OFF  = FTPERP_OFF + 1;
constexpr long long FTAVG_OFF  = CLAVG_OFF + KCB;
constexpr long long ENC_OFF    = FTAVG_OFF + KCB;
constexpr long long DIST_OFF   = ENC_OFF + (long long)NROWS * TK;   // 58,181,507
// DIST byte offset mod 16 == 12  ->  column k==1 of every row is 16B-aligned.

// packed pre-split bf16 scratch (lives in the quant output region, which is
// written only later by gather_kernel; 103 MB needed, 232 MB available)
constexpr size_t XS_ELE = (size_t)MT * NT * 4096;        // 128x32 tiles
constexpr size_t ES_ELE = (size_t)2 * NTB * NT * 8192;   // 256x32 tiles

constexpr float FMAXV = 3.4028234663852886e38f;
// Padding value: largest float that stays FINITE through a bf16 round-trip
// (0x7F7F0000). FLT_MAX rounds to +inf in bf16 -> inf-inf = nan in the
// harness compare.
constexpr float PADV  = 3.3895313892515355e38f;

DEVFN void gload_lds16(const void* g, void* l) {
    __builtin_amdgcn_global_load_lds(
        (const __attribute__((address_space(1))) unsigned*)g,
        (__attribute__((address_space(3))) unsigned*)l, 16, 0, 0);
}

// ---------------- top-3 primitives (BRANCHLESS: cndmask, no divergence) ----
DEVFN bool better(float v, int i, float bv, int bi) {
    return (v < bv) | ((v == bv) & (i < bi));  // stable: smaller index wins ties
}
DEVFN void ins3(float v, int i, float& v0, int& i0, float& v1, int& i1, float& v2, int& i2) {
    const bool b0 = better(v, i, v0, i0);
    const bool b1 = better(v, i, v1, i1);
    const bool b2 = better(v, i, v2, i2);
    // sorted invariant (v0<=v1<=v2 in 'better' order) gives b0 => b1 => b2
    const float nv1 = b0 ? v0 : (b1 ? v : v1);
    const int   ni1 = b0 ? i0 : (b1 ? i : i1);
    const float nv2 = b1 ? v1 : (b2 ? v : v2);
    const int   ni2 = b1 ? i1 : (b2 ? i : i2);
    v0 = b0 ? v : v0;  i0 = b0 ? i : i0;
    v1 = nv1;          i1 = ni1;
    v2 = nv2;          i2 = ni2;
}

// ---------------- init ----------------
__global__ void init_kernel(float* counts) {
    int i = blockIdx.x * blockDim.x + threadIdx.x;
    if (i < KOUT) counts[i] = 0.0f;
}

// ---------------- row norms (features + both codebooks) ----------------
__global__ void norms_kernel(const float* __restrict__ X,
                             const float* __restrict__ CE,
                             const float* __restrict__ FE,
                             float* __restrict__ xnorm,
                             float* __restrict__ enorm) {
    int row  = blockIdx.x * 4 + (threadIdx.x >> 6);
    int lane = threadIdx.x & 63;
    const int TOT = NROWS + 2 * KCB;
    if (row >= TOT) return;
    const float* src; float* dst;
    if (row < NROWS) { src = X + (long long)row * C; dst = xnorm + row; }
    else {
        int r = row - NROWS;
        src = (r < KCB) ? (CE + (long long)r * C) : (FE + (long long)(r - KCB) * C);
        dst = enorm + r;   // [0..4095] class, [4096..8191] feat
    }
    const float4* p = (const float4*)src;
    float s = 0.f;
    for (int j = lane; j < C / 4; j += 64) {
        float4 v = p[j];
        s += v.x*v.x + v.y*v.y + v.z*v.z + v.w*v.w;
    }
    for (int o = 32; o > 0; o >>= 1) s += __shfl_down(s, o);
    if (lane == 0) *dst = s;
}

// ---------------- pre-split: fp32 -> packed swizzled bf16 hi/lo tiles ------
// A tiles: 128x32 (8 KB/plane/tile), B tiles: 256x32 (16 KB/plane/tile).
// Element (r,k) -> byte (r*64 + 2k) ^ ((r&7)<<4) within its tile image.
__global__ __launch_bounds__(256)
void presplit_kernel(const float* __restrict__ X,
                     const float* __restrict__ CE,
                     const float* __restrict__ FE,
                     short* __restrict__ XsH, short* __restrict__ XsL,
                     short* __restrict__ EsH, short* __restrict__ EsL) {
    const int b = blockIdx.x;                    // A: 197*24, then B: 2*16*24
    const float* src; char* dH; char* dL; int nrr;
    if (b < MT * NT) {
        const int tile = b / NT, ks = b % NT;
        src = X + (size_t)tile * 128 * C + ks * 32;
        dH = (char*)(XsH + (size_t)b * 4096);
        dL = (char*)(XsL + (size_t)b * 4096);
        nrr = 2;                                  // 128 rows
    } else {
        const int bb = b - MT * NT;               // 0..767
        const int book = bb / (NTB * NT);
        const int rem  = bb % (NTB * NT);
        const int tile = rem / NT, ks = rem % NT;
        src = (book ? FE : CE) + (size_t)tile * 256 * C + ks * 32;
        dH = (char*)(EsH + (size_t)bb * 8192);
        dL = (char*)(EsL + (size_t)bb * 8192);
        nrr = 4;                                  // 256 rows
    }
    const int tid = threadIdx.x;
    const int row = tid >> 2, oc = tid & 3;       // base row, k-octet
    for (int rr = 0; rr < nrr; ++rr) {
        const int r = row + rr * 64;
        const float* s = src + (size_t)r * C + oc * 8;
        float4 v0 = *(const float4*)s;
        float4 v1 = *(const float4*)(s + 4);
        float f[8] = {v0.x, v0.y, v0.z, v0.w, v1.x, v1.y, v1.z, v1.w};
        s16x8 hi, lo;
        #pragma unroll
        for (int q = 0; q < 8; ++q) {
            unsigned u = __float_as_uint(f[q]);
            hi[q] = (short)(u >> 16);
            lo[q] = (short)(__float_as_uint(f[q] - __uint_as_float(u & 0xffff0000u)) >> 16);
        }
        const int off = (r * 64 + oc * 16) ^ ((r & 7) << 4);
        *(s16x8*)(dH + off) = hi;
        *(s16x8*)(dL + off) = lo;
    }
}

// ---------------- distance GEMM via bf16x3 MFMA, 3-phase interleave --------
// BM=128 x BN=256, 8 waves (2x4 of 64x64), BK=32, TRIPLE-buffered 144 KB LDS.
// m201-style phase discipline: per K-step, 3 phases {ds_read cluster + 2
// staged gloads -> lgkmcnt(0) -> setprio(1) -> 16 MFMA -> setprio(0) ->
// barrier}. vmcnt(6)+barrier once per step (tile t staged 2 steps ago).
__global__ __launch_bounds__(512, 2)
void gemm_dist_kernel(const short* __restrict__ XsH, const short* __restrict__ XsL,
                      const short* __restrict__ EsH, const short* __restrict__ EsL,
                      const float* __restrict__ xnorm,
                      const float* __restrict__ enorm,
                      float* __restrict__ dist) {
    // per buffer: AH 8K | AL 8K | BH 16K | BL 16K = 48 KB; x3 buffers
    __shared__ __align__(16) char smem[3 * 49152];

    // XCD-aware bijective swizzle: 3152 blocks, 3152 % 8 == 0, chunk = 394
    const int orig = blockIdx.y * gridDim.x + blockIdx.x;   // gridDim.x = 16
    const int wg   = (orig & 7) * 394 + (orig >> 3);
    const int mt = wg >> 4, nt = wg & 15;

    const int m0 = mt * 128, n0 = nt * 256;
    const int colbase = (mt == 0) ? 0 : KCB;
    const int btile = ((mt == 0) ? 0 : NTB) + nt;
    const int tid = threadIdx.x, l = tid & 63, w = tid >> 6;   // 8 waves
    const int wy = w >> 2, wx = w & 3;

    // ---- staging: 48 wave-chunks of 1 KB; wave w owns chunks w*6..w*6+5
    const char* sbase[6]; size_t sstr[6]; int ldso[6];
    #pragma unroll
    for (int i = 0; i < 6; ++i) {
        const int wc = w * 6 + i;
        const char* pb; int within; size_t st;
        if (wc < 8)       { pb = (const char*)XsH + (size_t)mt * NT * 8192;     within = wc * 1024;        st = 8192;  }
        else if (wc < 16) { pb = (const char*)XsL + (size_t)mt * NT * 8192;     within = (wc - 8) * 1024;  st = 8192;  }
        else if (wc < 32) { pb = (const char*)EsH + (size_t)btile * NT * 16384; within = (wc - 16) * 1024; st = 16384; }
        else              { pb = (const char*)EsL + (size_t)btile * NT * 16384; within = (wc - 32) * 1024; st = 16384; }
        sbase[i] = pb + within + l * 16;
        sstr[i]  = st;
        ldso[i]  = wc * 1024 + l * 16;
    }
    auto STAGE_ALL = [&](int buf, int t) {
        #pragma unroll
        for (int i = 0; i < 6; ++i)
            gload_lds16(sbase[i] + (size_t)t * sstr[i], smem + buf * 49152 + ldso[i]);
    };
    auto STAGE_PAIR = [&](int buf, int t, int p) {
        #pragma unroll
        for (int i = 0; i < 2; ++i)
            gload_lds16(sbase[p * 2 + i] + (size_t)t * sstr[p * 2 + i],
                        smem + buf * 49152 + ldso[p * 2 + i]);
    };

    // fragment geometry: wave (wy,wx) owns a 64x64 sub-tile of 128x256
    const int arow = wy * 64 + (l & 15);
    const int brow = wx * 64 + (l & 15);
    const int abase = (arow * 64 + ((l >> 4) * 16)) ^ ((l & 7) << 4);
    const int bbase = (brow * 64 + ((l >> 4) * 16)) ^ ((l & 7) << 4);

    f32x4 acc[4][4];
    #pragma unroll
    for (int i = 0; i < 4; ++i)
        #pragma unroll
        for (int j = 0; j < 4; ++j) acc[i][j] = (f32x4){0.f, 0.f, 0.f, 0.f};

    STAGE_ALL(0, 0);         // 6 in flight
    STAGE_ALL(1, 1);         // 12 in flight
    int cur = 0;
    for (int t = 0; t < NT; ++t) {
        const int nbuf = (cur + 2 >= 3) ? cur - 1 : cur + 2;   // (t+2)%3
        const bool pf = (t + 2 < NT);

        // tile t's 6 loads are the oldest outstanding (issued 2 steps ago);
        // vmcnt(6) drains exactly them. Barrier extends the guarantee to all
        // waves' chunks before anyone reads buf[cur].
        if (t + 1 < NT) { asm volatile("s_waitcnt vmcnt(6)" ::: "memory"); }
        else            { asm volatile("s_waitcnt vmcnt(0)" ::: "memory"); }
        __builtin_amdgcn_s_barrier();

        const char* sb = smem + cur * 49152;

        // ---- phase 1: ah, bh reads + stage pair 0 -> MFMA ah*bh
        s16x8 ah[4], bh[4];
        #pragma unroll
        for (int i = 0; i < 4; ++i) ah[i] = *(const s16x8*)(sb + abase + i * 1024);
        #pragma unroll
        for (int j = 0; j < 4; ++j) bh[j] = *(const s16x8*)(sb + 16384 + bbase + j * 1024);
        if (pf) STAGE_PAIR(nbuf, t + 2, 0);
        asm volatile("s_waitcnt lgkmcnt(0)" ::: "memory");
        __builtin_amdgcn_sched_barrier(0);
        __builtin_amdgcn_s_setprio(1);
        #pragma unroll
        for (int i = 0; i < 4; ++i)
            #pragma unroll
            for (int j = 0; j < 4; ++j)
                acc[i][j] = __builtin_amdgcn_mfma_f32_16x16x32_bf16(ah[i], bh[j], acc[i][j], 0, 0, 0);
        __builtin_amdgcn_s_setprio(0);
        __builtin_amdgcn_s_barrier();

        // ---- phase 2: al reads + stage pair 1 -> MFMA al*bh
        s16x8 al[4];
        #pragma unroll
        for (int i = 0; i < 4; ++i) al[i] = *(const s16x8*)(sb + 8192 + abase + i * 1024);
        if (pf) STAGE_PAIR(nbuf, t + 2, 1);
        asm volatile("s_waitcnt lgkmcnt(0)" ::: "memory");
        __builtin_amdgcn_sched_barrier(0);
        __builtin_amdgcn_s_setprio(1);
        #pragma unroll
        for (int i = 0; i < 4; ++i)
            #pragma unroll
            for (int j = 0; j < 4; ++j)
                acc[i][j] = __builtin_amdgcn_mfma_f32_16x16x32_bf16(al[i], bh[j], acc[i][j], 0, 0, 0);
        __builtin_amdgcn_s_setprio(0);
        __builtin_amdgcn_s_barrier();

        // ---- phase 3: bl reads + stage pair 2 -> MFMA ah*bl
        s16x8 bl[4];
        #pragma unroll
        for (int j = 0; j < 4; ++j) bl[j] = *(const s16x8*)(sb + 32768 + bbase + j * 1024);
        if (pf) STAGE_PAIR(nbuf, t + 2, 2);
        asm volatile("s_waitcnt lgkmcnt(0)" ::: "memory");
        __builtin_amdgcn_sched_barrier(0);
        __builtin_amdgcn_s_setprio(1);
        #pragma unroll
        for (int i = 0; i < 4; ++i)
            #pragma unroll
            for (int j = 0; j < 4; ++j)
                acc[i][j] = __builtin_amdgcn_mfma_f32_16x16x32_bf16(ah[i], bl[j], acc[i][j], 0, 0, 0);
        __builtin_amdgcn_s_setprio(0);
        __builtin_amdgcn_s_barrier();

        cur = (cur == 2) ? 0 : cur + 1;
    }

    // ---- epilogue: d = (xn + en) - 2*dot ; C/D map: col=lane&15, row=(lane>>4)*4+q
    const int lr = (l >> 4) * 4;
    const int lc = l & 15;
    float en_r[4];
    #pragma unroll
    for (int j = 0; j < 4; ++j) en_r[j] = enorm[colbase + n0 + wx * 64 + j * 16 + lc];
    #pragma unroll
    for (int i = 0; i < 4; ++i) {
        #pragma unroll
        for (int q = 0; q < 4; ++q) {
            const int gm = m0 + wy * 64 + i * 16 + lr + q;
            const float xnv = xnorm[gm];
            float* o = dist + (long long)gm * KOUT + colbase + n0 + wx * 64 + lc;
            #pragma unroll
            for (int j = 0; j < 4; ++j)
                o[j * 16] = (xnv + en_r[j]) - 2.0f * acc[i][j][q];  // scalar: dist base is 4B-aligned only
        }
    }

    // ---- fused pad: this block's mirror 128x256 stripe in the other codebook's half
    const int padbase = (mt == 0) ? KCB : 0;
    for (int r2 = w; r2 < 128; r2 += 8) {
        float* p = dist + (long long)(m0 + r2) * KOUT + padbase + n0;
        p[l] = PADV; p[l + 64] = PADV; p[l + 128] = PADV; p[l + 192] = PADV;
    }
}

// ---------------- top-3: branchless, 16-deep batched loads ----------------
// dist byte offset ≡ 12 (mod 16) -> col 1 of every row is 16B-aligned:
// cols 1..4092 as 1023 aligned float4 in ONE 16-deep batch, tail
// {0,4093,4094,4095} scalar. Rows in REVERSE for LLC-tail locality.
__global__ __launch_bounds__(256, 4)
void topk_kernel(const float* __restrict__ dist,
                 int* __restrict__ idxbuf,
                 float* __restrict__ out,
                 float* __restrict__ counts) {
    int rb = blockIdx.x * 4 + (threadIdx.x >> 6);
    if (rb >= NROWS) return;
    const int row = NROWS - 1 - rb;
    const int lane = threadIdx.x & 63;
    const int colbase = (row < NCL) ? 0 : KCB;
    const float* d = dist + (long long)row * KOUT + colbase;
    float v0 = FMAXV, v1 = FMAXV, v2 = FMAXV;
    int   i0 = 0x7fffffff, i1 = 0x7fffffff, i2 = 0x7fffffff;

    const float4* dv = (const float4*)(d + 1);   // 1023 aligned vectors

    float4 b[16];
    #pragma unroll
    for (int it = 0; it < 15; ++it) b[it] = dv[it * 64 + lane];
    const bool hasLast = (960 + lane) < 1023;
    b[15] = hasLast ? dv[960 + lane]
                    : (float4){FMAXV, FMAXV, FMAXV, FMAXV};
    #pragma unroll
    for (int it = 0; it < 15; ++it) {
        const int k = 1 + (it * 64 + lane) * 4;
        ins3(b[it].x, k,     v0, i0, v1, i1, v2, i2);
        ins3(b[it].y, k + 1, v0, i0, v1, i1, v2, i2);
        ins3(b[it].z, k + 2, v0, i0, v1, i1, v2, i2);
        ins3(b[it].w, k + 3, v0, i0, v1, i1, v2, i2);
    }
    {
        const int k = 1 + (960 + lane) * 4;
        const int kk = hasLast ? k : 0x7ffffff0; // masked entries stay maximal in tie-order
        ins3(b[15].x, kk,     v0, i0, v1, i1, v2, i2);
        ins3(b[15].y, kk + 1, v0, i0, v1, i1, v2, i2);
        ins3(b[15].z, kk + 2, v0, i0, v1, i1, v2, i2);
        ins3(b[15].w, kk + 3, v0, i0, v1, i1, v2, i2);
    }
    if (lane < 4) {                              // cols 0, 4093, 4094, 4095
        const int k = (lane == 0) ? 0 : 4092 + lane;
        ins3(d[k], k, v0, i0, v1, i1, v2, i2);
    }

    #pragma unroll
    for (int off = 32; off > 0; off >>= 1) {
        float w0 = __shfl_down(v0, off), w1 = __shfl_down(v1, off), w2 = __shfl_down(v2, off);
        int   j0 = __shfl_down(i0, off), j1 = __shfl_down(i1, off), j2 = __shfl_down(i2, off);
        ins3(w0, j0, v0, i0, v1, i1, v2, i2);
        ins3(w1, j1, v0, i0, v1, i1, v2, i2);
        ins3(w2, j2, v0, i0, v1, i1, v2, i2);
    }
    if (lane == 0) {
        long long rt = (long long)row * TK;
        idxbuf[rt + 0] = i0; idxbuf[rt + 1] = i1; idxbuf[rt + 2] = i2;
        out[ENC_OFF + rt + 0] = (float)(i0 + colbase);
        out[ENC_OFF + rt + 1] = (float)(i1 + colbase);
        out[ENC_OFF + rt + 2] = (float)(i2 + colbase);
        atomicAdd(&counts[i0 + colbase], 1.0f);
        atomicAdd(&counts[i1 + colbase], 1.0f);
        atomicAdd(&counts[i2 + colbase], 1.0f);
    }
}

// ---------------- gather + q_st + per-row SSE partial (no atomics) ----------------
__global__ __launch_bounds__(192)
void gather_kernel(const float* __restrict__ X,
                   const float* __restrict__ CE,
                   const float* __restrict__ FE,
                   const int* __restrict__ idxbuf,
                   float* __restrict__ out,
                   float* __restrict__ partials) {
    const int row = blockIdx.x;            // 0..25215
    const int tid = threadIdx.x;           // 0..191: one float4 column of the row
    const float4 xv = ((const float4*)(X + (size_t)row * C))[tid];
    const float* Ebase = (row < NCL) ? CE : FE;
    const long long rt0 = (long long)row * TK;
    float s = 0.f;
    #pragma unroll
    for (int t = 0; t < TK; ++t) {
        const int id = idxbuf[rt0 + t];
        const float4 ev = ((const float4*)(Ebase + (size_t)id * C))[tid];
        const float d0 = ev.x - xv.x, d1 = ev.y - xv.y, d2 = ev.z - xv.z, d3 = ev.w - xv.w;
        s += d0*d0 + d1*d1 + d2*d2 + d3*d3;
        // q_st = x + (quant - x), exactly the reference's float ops.
        float* q = out + QUANT_OFF + (rt0 + t) * C + tid * 4;
        q[0] = xv.x + d0; q[1] = xv.y + d1; q[2] = xv.z + d2; q[3] = xv.w + d3;
    }
    #pragma unroll
    for (int o = 32; o > 0; o >>= 1) s += __shfl_down(s, o);
    __shared__ float red[3];
    const int lane = tid & 63, w = tid >> 6;
    if (lane == 0) red[w] = s;
    __syncthreads();
    if (tid == 0) partials[row] = red[0] + red[1] + red[2];
}

// ---------------- finalize: avg_probs, perplexity, loss ----------------
__global__ void finalize_kernel(const float* __restrict__ counts,
                                const float* __restrict__ partials,
                                float* __restrict__ out) {
    __shared__ float  red[2][4];
    __shared__ double redd[2][4];
    int tid = threadIdx.x, lane = tid & 63, w = tid >> 6;
    float ecl = 0.f, eft = 0.f;
    for (int i = tid; i < KCB; i += blockDim.x) {
        float p = counts[i] * (1.0f / 128.0f);
        out[CLAVG_OFF + i] = p;
        ecl += p * logf(p + 1e-10f);
        float qv = counts[KCB + i] * (1.0f / 25088.0f);
        out[FTAVG_OFF + i] = qv;
        eft += qv * logf(qv + 1e-10f);
    }
    double scl = 0.0, sft = 0.0;
    for (int i = tid; i < NROWS; i += blockDim.x) {
        double v = (double)partials[i];
        if (i < NCL) scl += v; else sft += v;
    }
    for (int o = 32; o > 0; o >>= 1) {
        ecl += __shfl_down(ecl, o); eft += __shfl_down(eft, o);
        scl += __shfl_down(scl, o); sft += __shfl_down(sft, o);
    }
    if (lane == 0) { red[0][w] = ecl; red[1][w] = eft; redd[0][w] = scl; redd[1][w] = sft; }
    __syncthreads();
    if (tid == 0) {
        float tcl = red[0][0] + red[0][1] + red[0][2] + red[0][3];
        float tft = red[1][0] + red[1][1] + red[1][2] + red[1][3];
        double dcl = redd[0][0] + redd[0][1] + redd[0][2] + redd[0][3];
        double dft = redd[1][0] + redd[1][1] + redd[1][2] + redd[1][3];
        out[CLPERP_OFF] = expf(-tcl);
        out[FTPERP_OFF] = expf(-tft);
        float cl_loss = 0.25f * (float)(dcl / 294912.0);     // 1*128*3*768
        float ft_loss = 0.25f * (float)(dft / 57802752.0);   // 196*128*3*768
        out[0] = ft_loss + cl_loss;
    }
}

extern "C" void kernel_launch(void* const* d_in, const int* in_sizes, int n_in,
                              void* d_out, int out_size, void* d_ws, size_t ws_size,
                              hipStream_t stream) {
    const float* X  = (const float*)d_in[0];
    const float* CE = (const float*)d_in[1];
    const float* FE = (const float*)d_in[2];
    float* out = (float*)d_out;

    float* ws_f   = (float*)d_ws;
    float* xnorm  = ws_f;                         // 25216 (reused as SSE partials)
    float* enorm  = ws_f + NROWS;                 // 8192
    float* counts = ws_f + NROWS + KOUT;          // 8192
    int*   idxbuf = (int*)(ws_f + NROWS + 2 * KOUT);  // 75648 ints
    float* ssepart = xnorm;                       // xnorm dead after gemm; reuse
    float* dist   = out + DIST_OFF;

    // packed bf16 scratch inside the quant output region (dead until gather)
    short* XsH = (short*)(out + 4);
    short* XsL = XsH + XS_ELE;
    short* EsH = XsL + XS_ELE;
    short* EsL = EsH + ES_ELE;

    init_kernel<<<32, 256, 0, stream>>>(counts);
    norms_kernel<<<(NROWS + 2 * KCB) / 4, 256, 0, stream>>>(X, CE, FE, xnorm, enorm);
    presplit_kernel<<<MT * NT + 2 * NTB * NT, 256, 0, stream>>>(X, CE, FE, XsH, XsL, EsH, EsL);
    gemm_dist_kernel<<<dim3(NTB, MT), 512, 0, stream>>>(XsH, XsL, EsH, EsL, xnorm, enorm, dist);
    topk_kernel<<<NROWS / 4, 256, 0, stream>>>(dist, idxbuf, out, counts);
    gather_kernel<<<NROWS, 192, 0, stream>>>(X, CE, FE, idxbuf, out, ssepart);
    finalize_kernel<<<1, 256, 0, stream>>>(counts, ssepart, out);
}